// Round 8
// baseline (177.784 us; speedup 1.0000x reference)
//
#include <hip/hip_runtime.h>
#include <math.h>

#define BATCH 8192
#define NLEN 4096
#define NBLK 2048  // phase-1 blocks, 4 rows each
#define NMLP 32    // blocks that also do stats + MLP

// d_ws layout
#define OFF_S   (6 * BATCH * 4)       // feats [6][8192] f32 first
#define OFF_S2  (OFF_S + 6 * NBLK * 8)
#define OFF_MX  (OFF_S2 + 6 * NBLK * 8)
#define OFF_SEM (OFF_MX + 6 * NBLK * 4)

// ---------------------------------------------------------------------------
// ONE fused kernel. Phase 1 (all 2048 blocks): one row per wave, branchless
// HRV feature extraction (round-4 body: padding is exactly 0.0f so sum/sumsq
// are unmasked; diffs via cndmask chains; one ballot+shuffle boundary fixup;
// f32 partials folded into f64). Each block writes its 6-column partial
// sums (f64, exact over 4 rows) + max to scratch, then release-adds a
// semaphore. Phase 2+3 (blocks 0-31 only): stage MLP weights into LDS,
// acquire-spin for the semaphore (32 spinners << resident slots -> always
// forward progress, no cooperative launch needed), reduce the 2048 partials
// in deterministic fixed tree order, compute batch-norm stats, then run the
// normalize+MLP for 256 rows per block from LDS-broadcast weights.
// ---------------------------------------------------------------------------
__global__ __launch_bounds__(256) void hrv_fused_kernel(
    const float* __restrict__ rr,
    const float* __restrict__ w1, const float* __restrict__ b1,
    const float* __restrict__ w2, const float* __restrict__ b2,
    float* __restrict__ out, unsigned char* __restrict__ wsb) {
    float* feats = reinterpret_cast<float*>(wsb);
    double* scr_s = reinterpret_cast<double*>(wsb + OFF_S);
    double* scr_s2 = reinterpret_cast<double*>(wsb + OFF_S2);
    float* scr_mx = reinterpret_cast<float*>(wsb + OFF_MX);
    unsigned int* sem = reinterpret_cast<unsigned int*>(wsb + OFF_SEM);

    __shared__ float sh_v[4][6];
    __shared__ double sh_rs[4][6], sh_rs2[4][6];
    __shared__ float sh_rm[4][6];
    __shared__ float sh_stats[18];  // mean[6], std[6], max[6]
    __shared__ float sh_w[656];     // w1(96) b1(16) w2(512) b2(32)

    const int t = threadIdx.x;
    const int lane = t & 63;
    const int wid = t >> 6;
    const int b = blockIdx.x;

    // ================= phase 1: HRV features, one row per wave ============
    {
        const int row = b * 4 + wid;
        const float* r = rr + (size_t)row * NLEN + lane * 64;
        double dsum = 0.0, dsumsq = 0.0, dsumd2 = 0.0;
        int cnt = 0, nn50 = 0;
        float prev = 0.f, first = 0.f;
        bool has = false;
        float x[32];
        float4* xv = reinterpret_cast<float4*>(x);
        const float4* rv = reinterpret_cast<const float4*>(r);
#pragma unroll
        for (int half = 0; half < 2; ++half) {
#pragma unroll
            for (int i = 0; i < 8; ++i) xv[i] = rv[half * 8 + i];
#pragma unroll
            for (int c = 0; c < 2; ++c) {
                float s = 0.f, s2 = 0.f, d2 = 0.f;  // f32 partials, 16 elems
#pragma unroll
                for (int i = 0; i < 16; ++i) {
                    const float v = x[c * 16 + i];
                    const bool valid = v > 0.f;
                    s += v;  // padding is exactly 0 -> unmasked
                    s2 = fmaf(v, v, s2);
                    cnt += valid ? 1 : 0;
                    const float d = v - prev;  // same f32 sub as reference
                    const float dm = (valid && has) ? d : 0.f;
                    d2 = fmaf(dm, dm, d2);
                    nn50 += (fabsf(dm) > 0.05f) ? 1 : 0;
                    first = (valid && !has) ? v : first;
                    prev = valid ? v : prev;
                    has = has || valid;
                }
                dsum += s;
                dsumsq += s2;
                dsumd2 += d2;
            }
        }
        // boundary: my first valid vs last valid of nearest lower valid lane
        unsigned long long m = __ballot(has);
        unsigned long long pm = m & ((1ull << lane) - 1ull);
        int j = 63 - __clzll(pm | 1ull);
        float lastj = __shfl(prev, j, 64);
        if (has && pm) {
            float d = first - lastj;
            dsumd2 += (double)(d * d);
            nn50 += (fabsf(d) > 0.05f) ? 1 : 0;
        }
#pragma unroll
        for (int off = 32; off; off >>= 1) {
            dsum += __shfl_xor(dsum, off, 64);
            dsumsq += __shfl_xor(dsumsq, off, 64);
            dsumd2 += __shfl_xor(dsumd2, off, 64);
            cnt += __shfl_xor(cnt, off, 64);
            nn50 += __shfl_xor(nn50, off, 64);
        }
        const float cntf = (float)cnt;
        const float denom_m = fmaxf(cntf, 1.f);
        const float mean = (float)(dsum / (double)denom_m);
        const float varsum =
            (float)(dsumsq - (double)cnt * (double)mean * (double)mean);
        const float denom_v = fmaxf(cntf - 1.f, 1.f);
        const float sdnn = sqrtf(fmaxf(varsum / denom_v, 0.f));
        const float rmssd = sqrtf(fmaxf((float)(dsumd2 / (double)denom_v), 0.f));
        const float pnn50v = (float)nn50 / denom_v;
        const float hr = 60.f / fmaxf(mean, 1e-12f);
        const float cv = sdnn / fmaxf(mean, 1e-12f);
        float val = mean;  // lane 0
        val = (lane == 1) ? sdnn : val;
        val = (lane == 2) ? rmssd : val;
        val = (lane == 3) ? pnn50v : val;
        val = (lane == 4) ? hr : val;
        val = (lane == 5) ? cv : val;
        if (cnt <= 1) val = 0.f;
        if (lane < 6) {
            feats[lane * BATCH + row] = val;  // column-major
            sh_v[wid][lane] = val;
        }
    }
    __syncthreads();
    // per-block column partials (exact f64 over 4 rows), layout [col][block]
    if (t < 6) {
        double S = 0.0, S2 = 0.0;
        float M = -INFINITY;
#pragma unroll
        for (int w = 0; w < 4; ++w) {
            const float v = sh_v[w][t];
            S += (double)v;
            S2 += (double)v * (double)v;
            M = fmaxf(M, v);
        }
        scr_s[t * NBLK + b] = S;
        scr_s2[t * NBLK + b] = S2;
        scr_mx[t * NBLK + b] = M;
        __threadfence();  // make this thread's stores device-visible
    }
    __syncthreads();
    if (t == 0)
        __hip_atomic_fetch_add(sem, 1u, __ATOMIC_RELEASE,
                               __HIP_MEMORY_SCOPE_AGENT);

    if (b >= NMLP) return;

    // ====== stage MLP weights to LDS (independent of the semaphore) ======
#pragma unroll
    for (int i = t; i < 656; i += 256) {
        float v;
        if (i < 96) v = w1[i];
        else if (i < 112) v = b1[i - 96];
        else if (i < 624) v = w2[i - 112];
        else v = b2[i - 624];
        sh_w[i] = v;
    }

    // ================= wait for all 2048 phase-1 partials =================
    if (t == 0) {
        while (__hip_atomic_load(sem, __ATOMIC_ACQUIRE,
                                 __HIP_MEMORY_SCOPE_AGENT) < NBLK)
            __builtin_amdgcn_s_sleep(8);
    }
    __syncthreads();
    __threadfence();  // invalidate stale cached lines for scratch/feats

    // ================= phase 2: column stats (deterministic) ==============
    {
        double S[6], S2[6];
        float M[6];
#pragma unroll
        for (int c = 0; c < 6; ++c) { S[c] = 0.0; S2[c] = 0.0; M[c] = -INFINITY; }
#pragma unroll
        for (int c = 0; c < 6; ++c) {
#pragma unroll
            for (int k = 0; k < NBLK / 256; ++k) {
                const int p = t + k * 256;
                S[c] += scr_s[c * NBLK + p];
                S2[c] += scr_s2[c * NBLK + p];
                M[c] = fmaxf(M[c], scr_mx[c * NBLK + p]);
            }
        }
#pragma unroll
        for (int off = 32; off; off >>= 1) {
#pragma unroll
            for (int c = 0; c < 6; ++c) {
                S[c] += __shfl_xor(S[c], off, 64);
                S2[c] += __shfl_xor(S2[c], off, 64);
                M[c] = fmaxf(M[c], __shfl_xor(M[c], off, 64));
            }
        }
        if (lane == 0) {
#pragma unroll
            for (int c = 0; c < 6; ++c) {
                sh_rs[wid][c] = S[c];
                sh_rs2[wid][c] = S2[c];
                sh_rm[wid][c] = M[c];
            }
        }
        __syncthreads();
        if (t < 6) {
            double Sf = 0.0, S2f = 0.0;
            float Mf = -INFINITY;
#pragma unroll
            for (int w = 0; w < 4; ++w) {
                Sf += sh_rs[w][t];
                S2f += sh_rs2[w][t];
                Mf = fmaxf(Mf, sh_rm[w][t]);
            }
            const double meanb = Sf / (double)BATCH;
            double var =
                (S2f - (double)BATCH * meanb * meanb) / (double)(BATCH - 1);
            if (var < 0.0) var = 0.0;
            sh_stats[t] = (float)meanb;
            sh_stats[6 + t] = (float)sqrt(var);
            sh_stats[12 + t] = Mf;
        }
        __syncthreads();
    }

    // ================= phase 3: normalize + MLP, one row per thread =======
    {
        const int row = b * 256 + t;
        float f[6];
#pragma unroll
        for (int c = 0; c < 6; ++c) {
            float v = feats[c * BATCH + row];  // coalesced
            if (sh_stats[12 + c] > 0.f)
                v = (v - sh_stats[c]) / (sh_stats[6 + c] + 1e-8f);
            f[c] = v;
        }
        float h[16];
#pragma unroll
        for (int jj = 0; jj < 16; ++jj) {
            float a = sh_w[96 + jj];
#pragma unroll
            for (int c = 0; c < 6; ++c) a = fmaf(f[c], sh_w[c * 16 + jj], a);
            h[jj] = fmaxf(a, 0.f);
        }
        float o[32];
#pragma unroll
        for (int k = 0; k < 32; ++k) o[k] = sh_w[624 + k];
#pragma unroll
        for (int jj = 0; jj < 16; ++jj) {
            const float hj = h[jj];
#pragma unroll
            for (int k = 0; k < 32; ++k)
                o[k] = fmaf(hj, sh_w[112 + jj * 32 + k], o[k]);
        }
        float4* ov = reinterpret_cast<float4*>(out + (size_t)row * 32);
        const float4* op = reinterpret_cast<const float4*>(o);
#pragma unroll
        for (int i = 0; i < 8; ++i) ov[i] = op[i];
    }
}

extern "C" void kernel_launch(void* const* d_in, const int* in_sizes, int n_in,
                              void* d_out, int out_size, void* d_ws, size_t ws_size,
                              hipStream_t stream) {
    const float* rr = (const float*)d_in[0];
    const float* w1 = (const float*)d_in[1];
    const float* b1 = (const float*)d_in[2];
    const float* w2 = (const float*)d_in[3];
    const float* b2 = (const float*)d_in[4];
    float* out = (float*)d_out;
    unsigned char* wsb = (unsigned char*)d_ws;

    // zero the semaphore (graph-capturable async fill; 64B line)
    hipMemsetAsync(wsb + OFF_SEM, 0, 64, stream);
    hrv_fused_kernel<<<NBLK, 256, 0, stream>>>(rr, w1, b1, w2, b2, out, wsb);
}

// Round 9
// 47.069 us; speedup vs baseline: 3.7770x; 3.7770x over previous
//
#include <hip/hip_runtime.h>
#include <math.h>

#define BATCH 8192
#define NLEN 4096

// ---------------------------------------------------------------------------
// Kernel 1: ONE WAVE PER ROW (4 rows per 256-thread block). Lane l owns the
// contiguous 64-element chunk [l*64, l*64+64). No LDS, no __syncthreads.
// (Round-2 body — best measured of 4 structural variants.)
// Cross-lane compacted-diff boundary via __ballot + nearest-lower-set-bit +
// one variable-lane shuffle. f32 per-16-elem partial sums folded into double
// accumulators (batch-norm downstream divides by col stds ~0.005, amplifying
// per-row error ~200x; this scheme passes with wide margin).
// ---------------------------------------------------------------------------
__global__ __launch_bounds__(256) void hrv_feats_kernel(
    const float* __restrict__ rr, float* __restrict__ feats) {
    const int lane = threadIdx.x & 63;
    const int wid = threadIdx.x >> 6;
    const int row = blockIdx.x * 4 + wid;
    const float* r = rr + (size_t)row * NLEN + lane * 64;

    double dsum = 0.0, dsumsq = 0.0, dsumd2 = 0.0;
    int cnt = 0, nn50 = 0, has = 0;
    float first = 0.f, last = 0.f;

    float x[32];
    float4* xv = reinterpret_cast<float4*>(x);
    const float4* rv = reinterpret_cast<const float4*>(r);

#pragma unroll
    for (int half = 0; half < 2; ++half) {
#pragma unroll
        for (int i = 0; i < 8; ++i) xv[i] = rv[half * 8 + i];
#pragma unroll
        for (int c = 0; c < 2; ++c) {
            float s = 0.f, s2 = 0.f, d2 = 0.f;
#pragma unroll
            for (int i = 0; i < 16; ++i) {
                float v = x[c * 16 + i];
                if (v > 0.f) {
                    s += v;
                    s2 += v * v;
                    ++cnt;
                    if (has) {
                        float d = v - last;  // same f32 sub as reference
                        d2 += d * d;
                        nn50 += (fabsf(d) > 0.05f) ? 1 : 0;
                    } else {
                        first = v;
                        has = 1;
                    }
                    last = v;
                }
            }
            dsum += s;
            dsumsq += s2;
            dsumd2 += d2;
        }
    }

    // boundary diff: my first valid vs last valid of nearest lower lane
    unsigned long long m = __ballot(has != 0);
    unsigned long long pm = (lane == 0) ? 0ull : (m & ((1ull << lane) - 1ull));
    int j = 63 - __clzll(pm | 1ull);
    float lastj = __shfl(last, j, 64);
    if (has && pm) {
        float d = first - lastj;
        dsumd2 += (double)(d * d);
        nn50 += (fabsf(d) > 0.05f) ? 1 : 0;
    }

    // xor-butterfly reduction: ALL lanes end with totals (lanes 0-5 store)
#pragma unroll
    for (int off = 32; off; off >>= 1) {
        dsum += __shfl_xor(dsum, off, 64);
        dsumsq += __shfl_xor(dsumsq, off, 64);
        dsumd2 += __shfl_xor(dsumd2, off, 64);
        cnt += __shfl_xor(cnt, off, 64);
        nn50 += __shfl_xor(nn50, off, 64);
    }

    const float cntf = (float)cnt;
    const float denom_m = fmaxf(cntf, 1.f);
    const float mean = (float)(dsum / (double)denom_m);
    const float varsum = (float)(dsumsq - (double)cnt * (double)mean * (double)mean);
    const float denom_v = fmaxf(cntf - 1.f, 1.f);
    const float sdnn = sqrtf(fmaxf(varsum / denom_v, 0.f));
    const float rmssd = sqrtf(fmaxf((float)(dsumd2 / (double)denom_v), 0.f));
    const float pnn50 = (float)nn50 / denom_v;
    const float hr = 60.f / fmaxf(mean, 1e-12f);
    const float cv = sdnn / fmaxf(mean, 1e-12f);

    float val = mean;  // lane 0
    val = (lane == 1) ? sdnn : val;
    val = (lane == 2) ? rmssd : val;
    val = (lane == 3) ? pnn50 : val;
    val = (lane == 4) ? hr : val;
    val = (lane == 5) ? cv : val;
    if (cnt <= 1) val = 0.f;
    // COLUMN-MAJOR: feats[c][row] -> coalesced reads in kernel 2
    if (lane < 6) feats[lane * BATCH + row] = val;
}

// ---------------------------------------------------------------------------
// Kernel 2 (fused col-stats + MLP): 32 blocks x 1024 THREADS.
// Stats phase: per thread only 12 independent float4 loads (2 per column),
// all issued upfront, 16 waves/block to hide LLC/HBM latency (feats does
// not sit in the reading CU's L2 after the kernel boundary). f64 accum for
// the (sumsq - B*mean^2) cancellation. Deterministic identical stats per
// block. MLP phase: threads 0..255 each handle one row.
// ---------------------------------------------------------------------------
__global__ __launch_bounds__(1024) void stats_mlp_kernel(
    const float* __restrict__ feats,
    const float* __restrict__ w1, const float* __restrict__ b1,
    const float* __restrict__ w2, const float* __restrict__ b2,
    float* __restrict__ out) {
    __shared__ double sh_s[16][6], sh_s2[16][6];
    __shared__ float sh_m[16][6];
    __shared__ float sh_stats[18];  // mean[6], std[6], max[6]

    const int t = threadIdx.x;

    // ---- stats: 12 independent float4 loads (2 per column) ----
    float4 f4[6][2];
#pragma unroll
    for (int c = 0; c < 6; ++c) {
        const float4* col = reinterpret_cast<const float4*>(feats + c * BATCH);
#pragma unroll
        for (int k = 0; k < 2; ++k) f4[c][k] = col[t + k * 1024];
    }
    double s[6], s2[6];
    float mx[6];
#pragma unroll
    for (int c = 0; c < 6; ++c) {
        const float f[8] = {f4[c][0].x, f4[c][0].y, f4[c][0].z, f4[c][0].w,
                            f4[c][1].x, f4[c][1].y, f4[c][1].z, f4[c][1].w};
        s[c] = 0.0; s2[c] = 0.0; mx[c] = -INFINITY;
#pragma unroll
        for (int k = 0; k < 8; ++k) {
            s[c] += (double)f[k];
            s2[c] += (double)f[k] * (double)f[k];
            mx[c] = fmaxf(mx[c], f[k]);
        }
    }
#pragma unroll
    for (int off = 32; off; off >>= 1) {
#pragma unroll
        for (int c = 0; c < 6; ++c) {
            s[c] += __shfl_down(s[c], off, 64);
            s2[c] += __shfl_down(s2[c], off, 64);
            mx[c] = fmaxf(mx[c], __shfl_down(mx[c], off, 64));
        }
    }
    if ((t & 63) == 0) {
        const int w = t >> 6;
#pragma unroll
        for (int c = 0; c < 6; ++c) {
            sh_s[w][c] = s[c];
            sh_s2[w][c] = s2[c];
            sh_m[w][c] = mx[c];
        }
    }
    __syncthreads();
    if (t < 6) {
        double S = 0, S2 = 0;
        float M = -INFINITY;
#pragma unroll
        for (int w = 0; w < 16; ++w) {
            S += sh_s[w][t];
            S2 += sh_s2[w][t];
            M = fmaxf(M, sh_m[w][t]);
        }
        const double meanb = S / (double)BATCH;
        double var = (S2 - (double)BATCH * meanb * meanb) / (double)(BATCH - 1);
        if (var < 0.0) var = 0.0;
        sh_stats[t] = (float)meanb;
        sh_stats[6 + t] = (float)sqrt(var);
        sh_stats[12 + t] = M;
    }
    __syncthreads();

    // ---- MLP: threads 0..255, one row each ----
    if (t < 256) {
        const int row = blockIdx.x * 256 + t;
        float f[6];
#pragma unroll
        for (int c = 0; c < 6; ++c) {
            float v = feats[c * BATCH + row];
            if (sh_stats[12 + c] > 0.f)
                v = (v - sh_stats[c]) / (sh_stats[6 + c] + 1e-8f);
            f[c] = v;
        }
        float h[16];
#pragma unroll
        for (int jj = 0; jj < 16; ++jj) {
            float a = b1[jj];
#pragma unroll
            for (int c = 0; c < 6; ++c) a = fmaf(f[c], w1[c * 16 + jj], a);
            h[jj] = fmaxf(a, 0.f);
        }
        float o[32];
#pragma unroll
        for (int k = 0; k < 32; ++k) o[k] = b2[k];
#pragma unroll
        for (int jj = 0; jj < 16; ++jj) {
            const float hj = h[jj];
#pragma unroll
            for (int k = 0; k < 32; ++k) o[k] = fmaf(hj, w2[jj * 32 + k], o[k]);
        }
        float4* ov = reinterpret_cast<float4*>(out + (size_t)row * 32);
        const float4* op = reinterpret_cast<const float4*>(o);
#pragma unroll
        for (int i = 0; i < 8; ++i) ov[i] = op[i];
    }
}

extern "C" void kernel_launch(void* const* d_in, const int* in_sizes, int n_in,
                              void* d_out, int out_size, void* d_ws, size_t ws_size,
                              hipStream_t stream) {
    const float* rr = (const float*)d_in[0];
    const float* w1 = (const float*)d_in[1];
    const float* b1 = (const float*)d_in[2];
    const float* w2 = (const float*)d_in[3];
    const float* b2 = (const float*)d_in[4];
    float* out = (float*)d_out;
    float* feats = (float*)d_ws;  // column-major [6][BATCH] = 192 KiB

    hrv_feats_kernel<<<BATCH / 4, 256, 0, stream>>>(rr, feats);
    stats_mlp_kernel<<<BATCH / 256, 1024, 0, stream>>>(feats, w1, b1, w2, b2, out);
}

// Round 10
// 40.699 us; speedup vs baseline: 4.3683x; 1.1565x over previous
//
#include <hip/hip_runtime.h>
#include <math.h>

#define BATCH 8192
#define NLEN 4096
#define THREADS 256
#define PER_THREAD (NLEN / THREADS)  // 16

// ---------------------------------------------------------------------------
// Kernel 1 (round-1 body): ONE BLOCK PER ROW. Each thread owns 16 contiguous
// elements (4x float4): lane l loads at l*16B -> perfectly coalesced 4 KiB
// per wave-load, and 2M threads total give 4x the TLP of wave-per-row.
// Compaction boundaries via LDS scan-back (nearest preceding chunk with a
// valid element; P(chunk empty)=0.3^16~4e-9 so it's one hop in practice).
// f32 per-chunk partials -> f64 block reduction (downstream batch-norm
// divides by col stds ~0.005, amplifying per-row error ~200x).
// ---------------------------------------------------------------------------
__global__ __launch_bounds__(THREADS) void hrv_feats_kernel(
    const float* __restrict__ rr, float* __restrict__ feats) {
    __shared__ float sh_last[THREADS];
    __shared__ unsigned char sh_has[THREADS];
    __shared__ double sh_sum[4], sh_sumsq[4], sh_sumd2[4];
    __shared__ int sh_cnt[4], sh_nn50[4];

    const int row = blockIdx.x;
    const int t = threadIdx.x;
    const float* r = rr + (size_t)row * NLEN + t * PER_THREAD;

    float x[PER_THREAD];
    float4* xv = reinterpret_cast<float4*>(x);
    const float4* rv = reinterpret_cast<const float4*>(r);
#pragma unroll
    for (int i = 0; i < PER_THREAD / 4; ++i) xv[i] = rv[i];

    float sum = 0.f, sumsq = 0.f, sumd2 = 0.f;
    int cnt = 0, nn50 = 0;
    float first = 0.f, last = 0.f;
    int has = 0;
#pragma unroll
    for (int i = 0; i < PER_THREAD; ++i) {
        float v = x[i];
        if (v > 0.f) {
            sum += v;
            sumsq += v * v;
            ++cnt;
            if (has) {
                float d = v - last;  // same f32 subtraction as reference
                sumd2 += d * d;
                nn50 += (fabsf(d) > 0.05f) ? 1 : 0;
            } else {
                first = v;
                has = 1;
            }
            last = v;
        }
    }
    sh_last[t] = last;
    sh_has[t] = (unsigned char)has;
    __syncthreads();
    // boundary diff: my first valid vs last valid of nearest preceding
    // chunk that has one (almost always j == t-1)
    if (has && t > 0) {
        for (int j = t - 1; j >= 0; --j) {
            if (sh_has[j]) {
                float d = first - sh_last[j];
                sumd2 += d * d;
                nn50 += (fabsf(d) > 0.05f) ? 1 : 0;
                break;
            }
        }
    }

    double dsum = sum, dsumsq = sumsq, dsumd2 = sumd2;
    int icnt = cnt, inn = nn50;
#pragma unroll
    for (int off = 32; off > 0; off >>= 1) {
        dsum += __shfl_down(dsum, off, 64);
        dsumsq += __shfl_down(dsumsq, off, 64);
        dsumd2 += __shfl_down(dsumd2, off, 64);
        icnt += __shfl_down(icnt, off, 64);
        inn += __shfl_down(inn, off, 64);
    }
    const int wave = t >> 6;
    if ((t & 63) == 0) {
        sh_sum[wave] = dsum;
        sh_sumsq[wave] = dsumsq;
        sh_sumd2[wave] = dsumd2;
        sh_cnt[wave] = icnt;
        sh_nn50[wave] = inn;
    }
    __syncthreads();
    if (t == 0) {
        double S = 0, S2 = 0, D2 = 0;
        int C = 0, NN = 0;
        for (int w = 0; w < 4; ++w) {
            S += sh_sum[w];
            S2 += sh_sumsq[w];
            D2 += sh_sumd2[w];
            C += sh_cnt[w];
            NN += sh_nn50[w];
        }
        const float cntf = (float)C;
        const float denom_m = fmaxf(cntf, 1.f);
        const float mean = (float)(S / (double)denom_m);
        const float varsum = (float)(S2 - (double)C * (double)mean * (double)mean);
        const float denom_v = fmaxf(cntf - 1.f, 1.f);
        const float sdnn = sqrtf(fmaxf(varsum / denom_v, 0.f));
        const float rmssd = sqrtf(fmaxf((float)(D2 / (double)denom_v), 0.f));
        const float pnn50 = (float)NN / denom_v;
        const float hr = 60.f / fmaxf(mean, 1e-12f);
        const float cv = sdnn / fmaxf(mean, 1e-12f);
        float f0 = mean, f1 = sdnn, f2 = rmssd, f3 = pnn50, f4 = hr, f5 = cv;
        if (C <= 1) { f0 = f1 = f2 = f3 = f4 = f5 = 0.f; }
        float* o = feats + row * 6;
        o[0] = f0; o[1] = f1; o[2] = f2;
        o[3] = f3; o[4] = f4; o[5] = f5;
    }
}

// ---------------------------------------------------------------------------
// Kernel 2 (round-2 body): fused col-stats + MLP, 32 blocks x 256 threads.
// Each block redundantly computes column mean/std(ddof=1)/max over all 8192
// rows (feats is 192 KiB, cache-resident; f64 accum for the catastrophic
// (sumsq - B*mean^2) cancellation), then applies normalize + 6->16 ReLU ->
// 32 MLP to its own 256 rows. Deterministic identical stats per block.
// ---------------------------------------------------------------------------
__global__ __launch_bounds__(256) void stats_mlp_kernel(
    const float* __restrict__ feats,
    const float* __restrict__ w1, const float* __restrict__ b1,
    const float* __restrict__ w2, const float* __restrict__ b2,
    float* __restrict__ out) {
    __shared__ double sh_s[4][6], sh_s2[4][6];
    __shared__ float sh_m[4][6];
    __shared__ float sh_stats[18];  // mean[6], std[6], max[6]

    const int t = threadIdx.x;
    double s[6] = {0, 0, 0, 0, 0, 0};
    double s2[6] = {0, 0, 0, 0, 0, 0};
    float mx[6] = {-INFINITY, -INFINITY, -INFINITY, -INFINITY, -INFINITY, -INFINITY};

#pragma unroll 4
    for (int i = t; i < BATCH; i += 256) {
        const float* fp = feats + i * 6;
#pragma unroll
        for (int c = 0; c < 6; ++c) {
            float f = fp[c];
            s[c] += (double)f;
            s2[c] += (double)f * (double)f;
            mx[c] = fmaxf(mx[c], f);
        }
    }
#pragma unroll
    for (int off = 32; off; off >>= 1) {
#pragma unroll
        for (int c = 0; c < 6; ++c) {
            s[c] += __shfl_down(s[c], off, 64);
            s2[c] += __shfl_down(s2[c], off, 64);
            mx[c] = fmaxf(mx[c], __shfl_down(mx[c], off, 64));
        }
    }
    if ((t & 63) == 0) {
        const int w = t >> 6;
#pragma unroll
        for (int c = 0; c < 6; ++c) {
            sh_s[w][c] = s[c];
            sh_s2[w][c] = s2[c];
            sh_m[w][c] = mx[c];
        }
    }
    __syncthreads();
    if (t < 6) {
        double S = 0, S2 = 0;
        float M = -INFINITY;
        for (int w = 0; w < 4; ++w) {
            S += sh_s[w][t];
            S2 += sh_s2[w][t];
            M = fmaxf(M, sh_m[w][t]);
        }
        const double meanb = S / (double)BATCH;
        double var = (S2 - (double)BATCH * meanb * meanb) / (double)(BATCH - 1);
        if (var < 0.0) var = 0.0;
        sh_stats[t] = (float)meanb;
        sh_stats[6 + t] = (float)sqrt(var);
        sh_stats[12 + t] = M;
    }
    __syncthreads();

    const int row = blockIdx.x * 256 + t;
    const float* fp = feats + row * 6;
    float f[6];
#pragma unroll
    for (int c = 0; c < 6; ++c) {
        float v = fp[c];
        if (sh_stats[12 + c] > 0.f) v = (v - sh_stats[c]) / (sh_stats[6 + c] + 1e-8f);
        f[c] = v;
    }
    float h[16];
#pragma unroll
    for (int j = 0; j < 16; ++j) {
        float a = b1[j];
#pragma unroll
        for (int c = 0; c < 6; ++c) a = fmaf(f[c], w1[c * 16 + j], a);
        h[j] = fmaxf(a, 0.f);
    }
    float o[32];
#pragma unroll
    for (int k = 0; k < 32; ++k) o[k] = b2[k];
#pragma unroll
    for (int j = 0; j < 16; ++j) {
        const float hj = h[j];
#pragma unroll
        for (int k = 0; k < 32; ++k) o[k] = fmaf(hj, w2[j * 32 + k], o[k]);
    }
    float4* ov = reinterpret_cast<float4*>(out + (size_t)row * 32);
    const float4* op = reinterpret_cast<const float4*>(o);
#pragma unroll
    for (int i = 0; i < 8; ++i) ov[i] = op[i];
}

extern "C" void kernel_launch(void* const* d_in, const int* in_sizes, int n_in,
                              void* d_out, int out_size, void* d_ws, size_t ws_size,
                              hipStream_t stream) {
    const float* rr = (const float*)d_in[0];
    const float* w1 = (const float*)d_in[1];
    const float* b1 = (const float*)d_in[2];
    const float* w2 = (const float*)d_in[3];
    const float* b2 = (const float*)d_in[4];
    float* out = (float*)d_out;
    float* feats = (float*)d_ws;  // row-major [BATCH][6] = 192 KiB

    hrv_feats_kernel<<<BATCH, THREADS, 0, stream>>>(rr, feats);
    stats_mlp_kernel<<<BATCH / 256, THREADS, 0, stream>>>(feats, w1, b1, w2, b2, out);
}